// Round 2
// baseline (896.655 us; speedup 1.0000x reference)
//
#include <hip/hip_runtime.h>

#define NTOK 8192
#define DMODEL 512
#define NWORDS 128  // NTOK/64 mask words per row
#define ESTRIDE (2 * NTOK)  // Eh row stride in halfs: row r lives in attn row r's region

typedef _Float16 f16;
typedef _Float16 f16x4 __attribute__((ext_vector_type(4)));
typedef _Float16 f16x8 __attribute__((ext_vector_type(8)));
typedef float f32x4 __attribute__((ext_vector_type(4)));
typedef unsigned long long u64;

// async global->LDS, 16B per lane; lds dest = wave-uniform base + lane*16
__device__ __forceinline__ void async_ld16(const void* g, void* l) {
  __builtin_amdgcn_global_load_lds((const __attribute__((address_space(1))) void*)g,
                                   (__attribute__((address_space(3))) void*)l, 16, 0, 0);
}

// ---------------- pack fp32 -> f16 (elementwise, float4 vectorized) ----------------
__global__ void pack_f16(const float* __restrict__ s, f16* __restrict__ d, int n) {
  int i = (blockIdx.x * 256 + threadIdx.x) * 4;
  if (i >= n) return;
  float4 v = *(const float4*)(s + i);
  f16x4 h; h.x = (f16)v.x; h.y = (f16)v.y; h.z = (f16)v.z; h.w = (f16)v.w;
  *(f16x4*)(d + i) = h;
}

// ------------- mask int32 -> bitmask: 256MB -> 8MB, pure streaming -------------
__global__ __launch_bounds__(256) void pack_mask(const int* __restrict__ mask,
                                                 u64* __restrict__ bits) {
  int wave = (blockIdx.x * 256 + threadIdx.x) >> 6;
  int lane = threadIdx.x & 63;
  size_t W0 = (size_t)wave * 8;
#pragma unroll
  for (int i = 0; i < 8; ++i) {
    int m = mask[(W0 + i) * 64 + lane];  // coalesced 256B/wave
    u64 b = __ballot(m != 0);            // bit l = col W*64+l
    if (lane == 0) bits[W0 + i] = b;
  }
}

// ---------------- transpose V [NTOK][D] -> Vt [D][NTOK] ----------------
__global__ __launch_bounds__(256) void transpose_f16(const f16* __restrict__ src,
                                                     f16* __restrict__ dst) {
  __shared__ f16 T[64][72];  // +8 pad breaks bank alignment
  int t = threadIdx.x;
  int tok0 = blockIdx.x * 64, d0 = blockIdx.y * 64;
#pragma unroll
  for (int i = 0; i < 2; ++i) {
    int row = (t >> 3) + i * 32;
    int col = (t & 7) * 8;
    f16x8 v = *(const f16x8*)(src + (size_t)(tok0 + row) * DMODEL + d0 + col);
    *(f16x8*)(&T[row][col]) = v;
  }
  __syncthreads();
#pragma unroll
  for (int i = 0; i < 2; ++i) {
    int od = (t >> 3) + i * 32;
    int ot = (t & 7) * 8;
    f16x8 v;
#pragma unroll
    for (int j = 0; j < 8; ++j) v[j] = T[ot + j][od];
    *(f16x8*)(dst + (size_t)(d0 + od) * NTOK + tok0 + ot) = v;
  }
}

// stage 128x64 f16 tile from row-major G (row stride rs halfs) at (r0,k0) into lds
__device__ __forceinline__ void stage128x64(const f16* G, int r0, int k0, int rs,
                                            f16* lds, int t) {
  int wv = t >> 6;
  const f16* g = G + (size_t)(r0 + (t >> 3)) * rs + k0 + (t & 7) * 8;
#pragma unroll
  for (int i = 0; i < 4; ++i)
    async_ld16(g + (size_t)i * 32 * rs, (char*)lds + i * 4096 + wv * 1024);
}

// shared 128x128 C = A * B^T K-loop, BK=64, acc[4][4] per thread (4 waves)
template <int RS>
__device__ __forceinline__ void gemm128(const f16* A, const f16* B, int m0, int n0,
                                        f16* As, f16* Bs, int t, f32x4 (&acc)[4][4]) {
  int lane = t & 63, wv = t >> 6, quad = lane >> 4, l15 = lane & 15;
  int m_off = (wv & 1) * 64, n_off = (wv >> 1) * 64;
  for (int kt = 0; kt < RS; kt += 64) {
    __syncthreads();
    stage128x64(A, m0, kt, RS, As, t);
    stage128x64(B, n0, kt, RS, Bs, t);
    __syncthreads();
#pragma unroll
    for (int ks = 0; ks < 2; ++ks) {
      f16x8 af[4], bf[4];
#pragma unroll
      for (int mt = 0; mt < 4; ++mt)
        af[mt] = *(const f16x8*)(As + (m_off + mt * 16 + l15) * 64 + ks * 32 + quad * 8);
#pragma unroll
      for (int nt = 0; nt < 4; ++nt)
        bf[nt] = *(const f16x8*)(Bs + (n_off + nt * 16 + l15) * 64 + ks * 32 + quad * 8);
#pragma unroll
      for (int mt = 0; mt < 4; ++mt)
#pragma unroll
        for (int nt = 0; nt < 4; ++nt)
          acc[mt][nt] = __builtin_amdgcn_mfma_f32_16x16x32_f16(af[mt], bf[nt], acc[mt][nt], 0, 0, 0);
    }
  }
}

// ---------------- QKV: C[i,j] = sum_k X[i,k] * W[j,k] ----------------
__global__ __launch_bounds__(256) void qkv_gemm(const f16* __restrict__ X,
                                                const f16* __restrict__ Wall,
                                                f16* __restrict__ Out) {
  __shared__ f16 As[128 * 64];
  __shared__ f16 Bs[128 * 64];
  int t = threadIdx.x;
  int z = blockIdx.z;
  const f16* B = Wall + (size_t)z * DMODEL * DMODEL;
  f16* C = Out + (size_t)z * NTOK * DMODEL;
  int m0 = blockIdx.y * 128, n0 = blockIdx.x * 128;
  int lane = t & 63, wv = t >> 6, quad = lane >> 4, l15 = lane & 15;
  int m_off = (wv & 1) * 64, n_off = (wv >> 1) * 64;
  f32x4 acc[4][4] = {};
  gemm128<DMODEL>(X, B, m0, n0, As, Bs, t, acc);
#pragma unroll
  for (int mt = 0; mt < 4; ++mt)
#pragma unroll
    for (int nt = 0; nt < 4; ++nt)
#pragma unroll
      for (int r = 0; r < 4; ++r) {
        int row = m0 + m_off + mt * 16 + quad * 4 + r;
        int col = n0 + n_off + nt * 16 + l15;
        C[(size_t)row * DMODEL + col] = (f16)acc[mt][nt][r];
      }
}

// ---- scores: Eh(f16) = exp(masked QK^T/sqrt(D)); rowsum atomics; coalesced store ----
// Eh row r is stored at half-offset r*ESTRIDE (the first half of attn row r's fp32
// region) so the later in-place fp32 expansion only aliases its OWN row.
__global__ __launch_bounds__(256) void scores2(const f16* __restrict__ Q,
                                               const f16* __restrict__ Kh,
                                               const u64* __restrict__ bits,
                                               f16* __restrict__ Eh,
                                               float* __restrict__ rowsum) {
  __shared__ f16 SM[128 * 128];  // 32KB: As|Bs during GEMM, swizzled E tile after
  f16* As = SM;
  f16* Bs = SM + 128 * 64;
  int t = threadIdx.x;
  int m0 = blockIdx.y * 128, n0 = blockIdx.x * 128;
  int lane = t & 63, wv = t >> 6, quad = lane >> 4, l15 = lane & 15;
  int m_off = (wv & 1) * 64, n_off = (wv >> 1) * 64;
  f32x4 acc[4][4] = {};
  gemm128<DMODEL>(Q, Kh, m0, n0, As, Bs, t, acc);
  const float scale = 0.044194173824159216f;  // 1/sqrt(512)
  __syncthreads();  // all waves done with As/Bs; SM becomes the E tile
#pragma unroll
  for (int mt = 0; mt < 4; ++mt)
#pragma unroll
    for (int r = 0; r < 4; ++r) {
      int lrow = m_off + mt * 16 + quad * 4 + r;
      int row = m0 + lrow;
      u64 w = bits[(size_t)row * NWORDS + ((n0 + n_off) >> 6)];  // 64 cols of this wave
      float rs = 0.f;
#pragma unroll
      for (int nt = 0; nt < 4; ++nt) {
        float s = acc[mt][nt][r] * scale;
        float e = ((w >> (nt * 16 + l15)) & 1) ? 0.f : __expf(s);
        rs += e;
        int col = n_off + nt * 16 + l15;
        // XOR-swizzle 8-half blocks with row bits -> conflict-lean, bijective per row
        int phys = (((col >> 3) ^ (lrow & 15)) << 3) | (col & 7);
        SM[lrow * 128 + phys] = (f16)e;
      }
      rs += __shfl_xor(rs, 1);
      rs += __shfl_xor(rs, 2);
      rs += __shfl_xor(rs, 4);
      rs += __shfl_xor(rs, 8);
      if (l15 == 0) atomicAdd(&rowsum[row], rs);
    }
  __syncthreads();
#pragma unroll
  for (int p = 0; p < 8; ++p) {  // coalesced f16x8 stores: 1KB per wave-instr
    int lrow = p * 16 + (t >> 4);
    int cb = t & 15;
    f16x8 v = *(const f16x8*)(SM + lrow * 128 + ((cb ^ (lrow & 15)) << 3));
    *(f16x8*)(Eh + (size_t)(m0 + lrow) * ESTRIDE + n0 + cb * 8) = v;
  }
}

// ------- cntx = (Eh @ V) * rinv; Eh staged straight to LDS; K-chunked atomics -------
__global__ __launch_bounds__(512, 2) void pv_kernel(const f16* __restrict__ Eh,
                                                    const float* __restrict__ rowsum,
                                                    const f16* __restrict__ Vt,
                                                    float* __restrict__ cntx) {
  __shared__ f16 Es[128 * 32];  // 8 KB
  __shared__ f16 Vs[512 * 32];  // 32 KB
  int t = threadIdx.x;
  int r0 = blockIdx.x * 128;
  int k0 = blockIdx.y * 2048;
  int lane = t & 63, wv = t >> 6, quad = lane >> 4, l15 = lane & 15;
  int m_off = (wv & 1) * 64, n_off = (wv >> 1) * 128;
  f32x4 acc[4][8] = {};
  for (int kt = k0; kt < k0 + 2048; kt += 32) {
    __syncthreads();
    async_ld16(Eh + (size_t)(r0 + (t >> 2)) * ESTRIDE + kt + (t & 3) * 8,
               (char*)Es + wv * 1024);
#pragma unroll
    for (int i = 0; i < 4; ++i)
      async_ld16(Vt + (size_t)((i * 512 + t) >> 2) * NTOK + kt + (t & 3) * 8,
                 (char*)Vs + i * 8192 + wv * 1024);
    __syncthreads();
    f16x8 af[4], bf[8];
#pragma unroll
    for (int mt = 0; mt < 4; ++mt)
      af[mt] = *(const f16x8*)(Es + (m_off + mt * 16 + l15) * 32 + quad * 8);
#pragma unroll
    for (int nt = 0; nt < 8; ++nt)
      bf[nt] = *(const f16x8*)(Vs + (n_off + nt * 16 + l15) * 32 + quad * 8);
#pragma unroll
    for (int mt = 0; mt < 4; ++mt)
#pragma unroll
      for (int nt = 0; nt < 8; ++nt)
        acc[mt][nt] = __builtin_amdgcn_mfma_f32_16x16x32_f16(af[mt], bf[nt], acc[mt][nt], 0, 0, 0);
  }
#pragma unroll
  for (int mt = 0; mt < 4; ++mt)
#pragma unroll
    for (int r = 0; r < 4; ++r) {
      int row = r0 + m_off + mt * 16 + quad * 4 + r;
      float ri = 1.0f / rowsum[row];
#pragma unroll
      for (int nt = 0; nt < 8; ++nt) {
        int col = n_off + nt * 16 + l15;
        atomicAdd(&cntx[(size_t)row * DMODEL + col], acc[mt][nt][r] * ri);
      }
    }
}

// ---- in-place f16 E -> fp32 attn * rinv, per-row region.
// Row r: f16 col x at half 2r*NTOK + x; fp32 col x at half 2r*NTOK + 2x.
// fp32 write of col c clobbers f16 cols [2c,2c+2) >= c; chunks processed in
// DESCENDING order, read->barrier->write per chunk:
//  - chunk c's writes hit f16 cols [2c,2c+1024): own chunk read pre-barrier,
//    rest belongs to already-finished chunks.
//  - earlier (higher-c) writes land at f16 cols >= 2c+1024, never under a
//    later chunk's unread data.  All aliasing is within the block's own rows.
__global__ __launch_bounds__(256) void expand_attn(float* __restrict__ attn,
                                                   const float* __restrict__ rowsum) {
  int t = threadIdx.x;
  int row = blockIdx.x * 4 + (t >> 6);
  size_t rb = (size_t)row * NTOK;  // float offset of row r
  const f16* Ehrow = (const f16*)(attn + rb);
  float ri = 1.0f / rowsum[row];
  int c0 = (t & 63) * 8;
  for (int c = NTOK - 512; c >= 0; c -= 512) {
    f16x8 v = *(const f16x8*)(Ehrow + c + c0);
    __syncthreads();  // all reads of this chunk before any f32 write clobbers it
    float4 lo, hi;
    lo.x = (float)v[0] * ri; lo.y = (float)v[1] * ri;
    lo.z = (float)v[2] * ri; lo.w = (float)v[3] * ri;
    hi.x = (float)v[4] * ri; hi.y = (float)v[5] * ri;
    hi.z = (float)v[6] * ri; hi.w = (float)v[7] * ri;
    *(float4*)(attn + rb + c + c0) = lo;
    *(float4*)(attn + rb + c + c0 + 4) = hi;
  }
}

extern "C" void kernel_launch(void* const* d_in, const int* in_sizes, int n_in,
                              void* d_out, int out_size, void* d_ws, size_t ws_size,
                              hipStream_t stream) {
  const float* x  = (const float*)d_in[0];
  const int* mask = (const int*)d_in[1];
  const float* Wq = (const float*)d_in[2];
  const float* Wk = (const float*)d_in[3];
  const float* Wv = (const float*)d_in[4];
  float* cntx = (float*)d_out;
  float* attn = (float*)d_out + (size_t)NTOK * DMODEL;

  // workspace (f16): xh 8MB | Wh 1.5MB | Q,K,V 24MB | Vt 8MB | rowsum 32KB  (~42MB)
  f16* xh = (f16*)d_ws;
  f16* Wh = xh + (size_t)NTOK * DMODEL;
  f16* QKV = Wh + (size_t)3 * DMODEL * DMODEL;
  f16* Qh = QKV;
  f16* Kh = QKV + (size_t)NTOK * DMODEL;
  f16* Vh = QKV + (size_t)2 * NTOK * DMODEL;
  f16* Vt = QKV + (size_t)3 * NTOK * DMODEL;
  float* rowsum = (float*)(Vt + (size_t)NTOK * DMODEL);

  // bitmask (8MB) lives in the cntx output region: dead until after scores2.
  u64* bits = (u64*)cntx;
  // f16 E lives interleaved in the attn output region (first half of each fp32 row).
  f16* Eh = (f16*)attn;

  hipMemsetAsync(rowsum, 0, NTOK * sizeof(float), stream);

  pack_f16<<<dim3(NTOK * DMODEL / 1024), 256, 0, stream>>>(x, xh, NTOK * DMODEL);
  pack_f16<<<dim3(DMODEL * DMODEL / 1024), 256, 0, stream>>>(Wq, Wh, DMODEL * DMODEL);
  pack_f16<<<dim3(DMODEL * DMODEL / 1024), 256, 0, stream>>>(Wk, Wh + DMODEL * DMODEL, DMODEL * DMODEL);
  pack_f16<<<dim3(DMODEL * DMODEL / 1024), 256, 0, stream>>>(Wv, Wh + 2 * DMODEL * DMODEL, DMODEL * DMODEL);
  pack_mask<<<dim3(NTOK * NWORDS / 8 / 4), 256, 0, stream>>>(mask, bits);

  qkv_gemm<<<dim3(DMODEL / 128, NTOK / 128, 3), 256, 0, stream>>>(xh, Wh, QKV);
  transpose_f16<<<dim3(NTOK / 64, DMODEL / 64), 256, 0, stream>>>(Vh, Vt);
  scores2<<<dim3(NTOK / 128, NTOK / 128), 256, 0, stream>>>(Qh, Kh, bits, Eh, rowsum);

  // bits now dead; zero cntx for pv atomics
  hipMemsetAsync(cntx, 0, (size_t)NTOK * DMODEL * sizeof(float), stream);
  pv_kernel<<<dim3(NTOK / 128, 4), 512, 0, stream>>>(Eh, rowsum, Vt, cntx);
  expand_attn<<<dim3(NTOK / 4), 256, 0, stream>>>(attn, rowsum);
}

// Round 3
// 852.240 us; speedup vs baseline: 1.0521x; 1.0521x over previous
//
#include <hip/hip_runtime.h>

#define NTOK 8192
#define DMODEL 512
#define NWORDS 128  // NTOK/64 mask words per row
#define ESTRIDE (2 * NTOK)  // Eh row stride in halfs: row r lives in attn row r's region

typedef _Float16 f16;
typedef _Float16 f16x4 __attribute__((ext_vector_type(4)));
typedef _Float16 f16x8 __attribute__((ext_vector_type(8)));
typedef float f32x4 __attribute__((ext_vector_type(4)));
typedef unsigned long long u64;

// async global->LDS, 16B per lane; lds dest = wave-uniform base + lane*16
__device__ __forceinline__ void async_ld16(const void* g, void* l) {
  __builtin_amdgcn_global_load_lds((const __attribute__((address_space(1))) void*)g,
                                   (__attribute__((address_space(3))) void*)l, 16, 0, 0);
}

// ---------------- pack fp32 -> f16 (elementwise, float4 vectorized) ----------------
__global__ void pack_f16(const float* __restrict__ s, f16* __restrict__ d, int n) {
  int i = (blockIdx.x * 256 + threadIdx.x) * 4;
  if (i >= n) return;
  float4 v = *(const float4*)(s + i);
  f16x4 h; h.x = (f16)v.x; h.y = (f16)v.y; h.z = (f16)v.z; h.w = (f16)v.w;
  *(f16x4*)(d + i) = h;
}

// ------------- mask int32 -> bitmask: 256MB -> 8MB, pure streaming -------------
__global__ __launch_bounds__(256) void pack_mask(const int* __restrict__ mask,
                                                 u64* __restrict__ bits) {
  int wave = (blockIdx.x * 256 + threadIdx.x) >> 6;
  int lane = threadIdx.x & 63;
  size_t W0 = (size_t)wave * 8;
#pragma unroll
  for (int i = 0; i < 8; ++i) {
    int m = mask[(W0 + i) * 64 + lane];  // coalesced 256B/wave
    u64 b = __ballot(m != 0);            // bit l = col W*64+l
    if (lane == 0) bits[W0 + i] = b;
  }
}

// ---------------- transpose V [NTOK][D] -> Vt [D][NTOK] ----------------
__global__ __launch_bounds__(256) void transpose_f16(const f16* __restrict__ src,
                                                     f16* __restrict__ dst) {
  __shared__ f16 T[64][72];  // +8 pad breaks bank alignment
  int t = threadIdx.x;
  int tok0 = blockIdx.x * 64, d0 = blockIdx.y * 64;
#pragma unroll
  for (int i = 0; i < 2; ++i) {
    int row = (t >> 3) + i * 32;
    int col = (t & 7) * 8;
    f16x8 v = *(const f16x8*)(src + (size_t)(tok0 + row) * DMODEL + d0 + col);
    *(f16x8*)(&T[row][col]) = v;
  }
  __syncthreads();
#pragma unroll
  for (int i = 0; i < 2; ++i) {
    int od = (t >> 3) + i * 32;
    int ot = (t & 7) * 8;
    f16x8 v;
#pragma unroll
    for (int j = 0; j < 8; ++j) v[j] = T[ot + j][od];
    *(f16x8*)(dst + (size_t)(d0 + od) * NTOK + tok0 + ot) = v;
  }
}

// ---- stage 128x64 f16 tile, XOR-swizzled (rule #21: linear LDS dest via
// global_load_lds + pre-swizzled GLOBAL column; reader applies the same XOR).
// LDS[row][u] = G[row][u ^ ((row&7)*8)]  (XOR on half-index bits 3..5).
__device__ __forceinline__ void stage128x64(const f16* G, int r0, int k0, int rs,
                                            f16* lds, int t) {
  int wv = t >> 6;
  int sw = (((t & 7) ^ ((t >> 3) & 7)) * 8);  // row&7 == (t>>3)&7 for all 4 iters
  const f16* g = G + (size_t)(r0 + (t >> 3)) * rs + k0 + sw;
#pragma unroll
  for (int i = 0; i < 4; ++i)
    async_ld16(g + (size_t)i * 32 * rs, (char*)lds + i * 4096 + wv * 1024);
}

// shared 128x128 C = A * B^T K-loop, BK=64, acc[4][4] per thread (4 waves)
template <int RS>
__device__ __forceinline__ void gemm128(const f16* A, const f16* B, int m0, int n0,
                                        f16* As, f16* Bs, int t, f32x4 (&acc)[4][4]) {
  int lane = t & 63, wv = t >> 6, quad = lane >> 4, l15 = lane & 15;
  int m_off = (wv & 1) * 64, n_off = (wv >> 1) * 64;
  for (int kt = 0; kt < RS; kt += 64) {
    __syncthreads();
    stage128x64(A, m0, kt, RS, As, t);
    stage128x64(B, n0, kt, RS, Bs, t);
    __syncthreads();
#pragma unroll
    for (int ks = 0; ks < 2; ++ks) {
      // de-swizzle: want G[row][ks*32+quad*8]; row&7 == l15&7 (m_off,n_off mult of 16)
      int sl = (((ks << 2) | quad) ^ (l15 & 7)) * 8;
      f16x8 af[4], bf[4];
#pragma unroll
      for (int mt = 0; mt < 4; ++mt)
        af[mt] = *(const f16x8*)(As + (m_off + mt * 16 + l15) * 64 + sl);
#pragma unroll
      for (int nt = 0; nt < 4; ++nt)
        bf[nt] = *(const f16x8*)(Bs + (n_off + nt * 16 + l15) * 64 + sl);
#pragma unroll
      for (int mt = 0; mt < 4; ++mt)
#pragma unroll
        for (int nt = 0; nt < 4; ++nt)
          acc[mt][nt] = __builtin_amdgcn_mfma_f32_16x16x32_f16(af[mt], bf[nt], acc[mt][nt], 0, 0, 0);
    }
  }
}

// ---------------- QKV: C[i,j] = sum_k X[i,k] * W[j,k] ----------------
__global__ __launch_bounds__(256) void qkv_gemm(const f16* __restrict__ X,
                                                const f16* __restrict__ Wall,
                                                f16* __restrict__ Out) {
  __shared__ f16 As[128 * 64];
  __shared__ f16 Bs[128 * 64];
  int t = threadIdx.x;
  int z = blockIdx.z;
  const f16* B = Wall + (size_t)z * DMODEL * DMODEL;
  f16* C = Out + (size_t)z * NTOK * DMODEL;
  int m0 = blockIdx.y * 128, n0 = blockIdx.x * 128;
  int lane = t & 63, wv = t >> 6, quad = lane >> 4, l15 = lane & 15;
  int m_off = (wv & 1) * 64, n_off = (wv >> 1) * 64;
  f32x4 acc[4][4] = {};
  gemm128<DMODEL>(X, B, m0, n0, As, Bs, t, acc);
#pragma unroll
  for (int mt = 0; mt < 4; ++mt)
#pragma unroll
    for (int nt = 0; nt < 4; ++nt)
#pragma unroll
      for (int r = 0; r < 4; ++r) {
        int row = m0 + m_off + mt * 16 + quad * 4 + r;
        int col = n0 + n_off + nt * 16 + l15;
        C[(size_t)row * DMODEL + col] = (f16)acc[mt][nt][r];
      }
}

// ---- scores: Eh(f16) = exp(masked QK^T/sqrt(D)); rowsum atomics; coalesced store ----
// Eh row r is stored at half-offset r*ESTRIDE (the first half of attn row r's fp32
// region) so the later in-place fp32 expansion only aliases its OWN row.
__global__ __launch_bounds__(256) void scores2(const f16* __restrict__ Q,
                                               const f16* __restrict__ Kh,
                                               const u64* __restrict__ bits,
                                               f16* __restrict__ Eh,
                                               float* __restrict__ rowsum) {
  __shared__ f16 SM[128 * 128];  // 32KB: As|Bs during GEMM, swizzled E tile after
  f16* As = SM;
  f16* Bs = SM + 128 * 64;
  int t = threadIdx.x;
  int m0 = blockIdx.y * 128, n0 = blockIdx.x * 128;
  int lane = t & 63, wv = t >> 6, quad = lane >> 4, l15 = lane & 15;
  int m_off = (wv & 1) * 64, n_off = (wv >> 1) * 64;
  f32x4 acc[4][4] = {};
  gemm128<DMODEL>(Q, Kh, m0, n0, As, Bs, t, acc);
  const float scale = 0.044194173824159216f;  // 1/sqrt(512)
  __syncthreads();  // all waves done with As/Bs; SM becomes the E tile
#pragma unroll
  for (int mt = 0; mt < 4; ++mt)
#pragma unroll
    for (int r = 0; r < 4; ++r) {
      int lrow = m_off + mt * 16 + quad * 4 + r;
      int row = m0 + lrow;
      u64 w = bits[(size_t)row * NWORDS + ((n0 + n_off) >> 6)];  // 64 cols of this wave
      float rs = 0.f;
#pragma unroll
      for (int nt = 0; nt < 4; ++nt) {
        float s = acc[mt][nt][r] * scale;
        float e = ((w >> (nt * 16 + l15)) & 1) ? 0.f : __expf(s);
        rs += e;
        int col = n_off + nt * 16 + l15;
        // XOR-swizzle 8-half blocks with row bits -> conflict-lean, bijective per row
        int phys = (((col >> 3) ^ (lrow & 15)) << 3) | (col & 7);
        SM[lrow * 128 + phys] = (f16)e;
      }
      rs += __shfl_xor(rs, 1);
      rs += __shfl_xor(rs, 2);
      rs += __shfl_xor(rs, 4);
      rs += __shfl_xor(rs, 8);
      if (l15 == 0) atomicAdd(&rowsum[row], rs);
    }
  __syncthreads();
#pragma unroll
  for (int p = 0; p < 8; ++p) {  // coalesced f16x8 stores: 1KB per wave-instr
    int lrow = p * 16 + (t >> 4);
    int cb = t & 15;
    f16x8 v = *(const f16x8*)(SM + lrow * 128 + ((cb ^ (lrow & 15)) << 3));
    *(f16x8*)(Eh + (size_t)(m0 + lrow) * ESTRIDE + n0 + cb * 8) = v;
  }
}

// ------- cntx = (Eh @ V) * rinv; BK=64, swizzled tiles; K-chunked atomics -------
__global__ __launch_bounds__(512, 2) void pv_kernel(const f16* __restrict__ Eh,
                                                    const float* __restrict__ rowsum,
                                                    const f16* __restrict__ Vt,
                                                    float* __restrict__ cntx) {
  __shared__ f16 Es[128 * 64];  // 16 KB
  __shared__ f16 Vs[512 * 64];  // 64 KB
  int t = threadIdx.x;
  int r0 = blockIdx.x * 128;
  int k0 = blockIdx.y * 2048;
  int lane = t & 63, wv = t >> 6, quad = lane >> 4, l15 = lane & 15;
  int m_off = (wv & 1) * 64, n_off = (wv >> 1) * 128;
  int sw = (((t & 7) ^ ((t >> 3) & 7)) * 8);  // pre-swizzled source column
  f32x4 acc[4][8] = {};
  for (int kt = k0; kt < k0 + 2048; kt += 64) {
    __syncthreads();
#pragma unroll
    for (int i = 0; i < 2; ++i)  // Es rows i*64 + (t>>3)
      async_ld16(Eh + (size_t)(r0 + i * 64 + (t >> 3)) * ESTRIDE + kt + sw,
                 (char*)Es + i * 8192 + wv * 1024);
#pragma unroll
    for (int i = 0; i < 8; ++i)  // Vs rows i*64 + (t>>3)
      async_ld16(Vt + (size_t)(i * 64 + (t >> 3)) * NTOK + kt + sw,
                 (char*)Vs + i * 8192 + wv * 1024);
    __syncthreads();
#pragma unroll
    for (int ks = 0; ks < 2; ++ks) {
      int sl = (((ks << 2) | quad) ^ (l15 & 7)) * 8;
      f16x8 af[4], bf[8];
#pragma unroll
      for (int mt = 0; mt < 4; ++mt)
        af[mt] = *(const f16x8*)(Es + (m_off + mt * 16 + l15) * 64 + sl);
#pragma unroll
      for (int nt = 0; nt < 8; ++nt)
        bf[nt] = *(const f16x8*)(Vs + (n_off + nt * 16 + l15) * 64 + sl);
#pragma unroll
      for (int mt = 0; mt < 4; ++mt)
#pragma unroll
        for (int nt = 0; nt < 8; ++nt)
          acc[mt][nt] = __builtin_amdgcn_mfma_f32_16x16x32_f16(af[mt], bf[nt], acc[mt][nt], 0, 0, 0);
    }
  }
#pragma unroll
  for (int mt = 0; mt < 4; ++mt)
#pragma unroll
    for (int r = 0; r < 4; ++r) {
      int row = r0 + m_off + mt * 16 + quad * 4 + r;
      float ri = 1.0f / rowsum[row];
#pragma unroll
      for (int nt = 0; nt < 8; ++nt) {
        int col = n_off + nt * 16 + l15;
        atomicAdd(&cntx[(size_t)row * DMODEL + col], acc[mt][nt][r] * ri);
      }
    }
}

// ---- in-place f16 E -> fp32 attn * rinv, two-phase via LDS.
// All f16 reads of the block's 4 rows land in LDS BEFORE the barrier; fp32
// writes after the barrier may freely clobber the f16 region (own rows only:
// row r's f16 data lives inside row r's fp32 region by construction).
__global__ __launch_bounds__(256) void expand_attn(float* __restrict__ attn,
                                                   const float* __restrict__ rowsum) {
  __shared__ f16 B[4][8192];  // 64 KB
  int t = threadIdx.x;
  int wv = t >> 6, lane = t & 63;
  int row = blockIdx.x * 4 + wv;  // wave wv owns row r0+wv
  const f16* src = (const f16*)(attn + (size_t)row * NTOK);
#pragma unroll
  for (int i = 0; i < 16; ++i)  // 16 x 1KB coalesced async issues per wave
    async_ld16(src + i * 512 + lane * 8, (char*)&B[wv][0] + i * 1024);
  __syncthreads();  // drains vmcnt: all f16 data safe in LDS
  float ri = 1.0f / rowsum[row];
  float* dst = attn + (size_t)row * NTOK;
#pragma unroll
  for (int c = 0; c < NTOK; c += 512) {
    f16x8 v = *(const f16x8*)(&B[wv][c + lane * 8]);
    float4 lo, hi;
    lo.x = (float)v[0] * ri; lo.y = (float)v[1] * ri;
    lo.z = (float)v[2] * ri; lo.w = (float)v[3] * ri;
    hi.x = (float)v[4] * ri; hi.y = (float)v[5] * ri;
    hi.z = (float)v[6] * ri; hi.w = (float)v[7] * ri;
    *(float4*)(dst + c + lane * 8) = lo;
    *(float4*)(dst + c + lane * 8 + 4) = hi;
  }
}

extern "C" void kernel_launch(void* const* d_in, const int* in_sizes, int n_in,
                              void* d_out, int out_size, void* d_ws, size_t ws_size,
                              hipStream_t stream) {
  const float* x  = (const float*)d_in[0];
  const int* mask = (const int*)d_in[1];
  const float* Wq = (const float*)d_in[2];
  const float* Wk = (const float*)d_in[3];
  const float* Wv = (const float*)d_in[4];
  float* cntx = (float*)d_out;
  float* attn = (float*)d_out + (size_t)NTOK * DMODEL;

  // workspace (f16): xh 8MB | Wh 1.5MB | Q,K,V 24MB | Vt 8MB | rowsum 32KB  (~42MB)
  f16* xh = (f16*)d_ws;
  f16* Wh = xh + (size_t)NTOK * DMODEL;
  f16* QKV = Wh + (size_t)3 * DMODEL * DMODEL;
  f16* Qh = QKV;
  f16* Kh = QKV + (size_t)NTOK * DMODEL;
  f16* Vh = QKV + (size_t)2 * NTOK * DMODEL;
  f16* Vt = QKV + (size_t)3 * NTOK * DMODEL;
  float* rowsum = (float*)(Vt + (size_t)NTOK * DMODEL);

  // bitmask (8MB) lives in the cntx output region: dead until after scores2.
  u64* bits = (u64*)cntx;
  // f16 E lives interleaved in the attn output region (first half of each fp32 row).
  f16* Eh = (f16*)attn;

  hipMemsetAsync(rowsum, 0, NTOK * sizeof(float), stream);

  pack_f16<<<dim3(NTOK * DMODEL / 1024), 256, 0, stream>>>(x, xh, NTOK * DMODEL);
  pack_f16<<<dim3(DMODEL * DMODEL / 1024), 256, 0, stream>>>(Wq, Wh, DMODEL * DMODEL);
  pack_f16<<<dim3(DMODEL * DMODEL / 1024), 256, 0, stream>>>(Wk, Wh + DMODEL * DMODEL, DMODEL * DMODEL);
  pack_f16<<<dim3(DMODEL * DMODEL / 1024), 256, 0, stream>>>(Wv, Wh + 2 * DMODEL * DMODEL, DMODEL * DMODEL);
  pack_mask<<<dim3(NTOK * NWORDS / 8 / 4), 256, 0, stream>>>(mask, bits);

  qkv_gemm<<<dim3(DMODEL / 128, NTOK / 128, 3), 256, 0, stream>>>(xh, Wh, QKV);
  transpose_f16<<<dim3(NTOK / 64, DMODEL / 64), 256, 0, stream>>>(Vh, Vt);
  scores2<<<dim3(NTOK / 128, NTOK / 128), 256, 0, stream>>>(Qh, Kh, bits, Eh, rowsum);

  // bits now dead; zero cntx for pv atomics
  hipMemsetAsync(cntx, 0, (size_t)NTOK * DMODEL * sizeof(float), stream);
  pv_kernel<<<dim3(NTOK / 128, 4), 512, 0, stream>>>(Eh, rowsum, Vt, cntx);
  expand_attn<<<dim3(NTOK / 4), 256, 0, stream>>>(attn, rowsum);
}